// Round 1
// 1661.367 us; speedup vs baseline: 1.0269x; 1.0269x over previous
//
#include <hip/hip_runtime.h>
#include <hip/hip_fp16.h>
#include <math.h>

// ---------------- problem constants ----------------
constexpr int H   = 256;
constexpr int ID  = 512;   // image_dim == text_dim
constexpr int NC  = 80;
constexpr int BT  = 131072;

constexpr int MROWS = 32;              // rows per block (2 row-tiles of 16)
constexpr int NBLK  = BT / MROWS;      // 4096, exact -> no tail predication

typedef _Float16 half8  __attribute__((ext_vector_type(8)));
typedef float    floatx4 __attribute__((ext_vector_type(4)));

#define MFMA16(a,b,c) __builtin_amdgcn_mfma_f32_16x16x32_f16((a),(b),(c),0,0,0)

__device__ inline half8 splat8(_Float16 v){ half8 r = {v,v,v,v,v,v,v,v}; return r; }

// ---------------- device-global fp16 weights (transposed [N][K]) ----------------
__device__ __align__(16) _Float16 g_WieT[H*ID];     // [256][512]
__device__ __align__(16) _Float16 g_WteT[H*ID];     // [256][512]
__device__ __align__(16) _Float16 g_WvT [H*H];      // [256][256]
__device__ __align__(16) _Float16 g_WipT[2*H*H];    // [512][256]
__device__ __align__(16) _Float16 g_WtpT[2*H*H];    // [512][256]
__device__ __align__(16) _Float16 g_WofT[2*H*H];    // [512][256]  = (Wo@W_fp)^T
__device__ __align__(16) _Float16 g_Wc1T[H*2*H];    // [256][512]
__device__ __align__(16) _Float16 g_Wc2T[NC*H];     // [80][256]
__device__ __align__(16) float g_wkeff[4*H];        // [4][256]  Wk folded with q, /8 (h-major!)
__device__ float g_sbias[4];                        // bk folded with q, /8
__device__ float g_biasof[2*H];                     // bo@W_fp + b_fp

// ---------------- LDS layout (dynamic) ----------------
// half-unit offsets:
//   encI  [32][264] @ 0       (bytes [0,16896))
//   encT  [32][264] @ 8448    (bytes [16896,33792))
//   pool  [32][264] @ 16896   (bytes [33792,50688)), later h1
//   fused [32][520] overlays encI+encT (bytes [0,33280))
constexpr int OFF_EI = 0;
constexpr int OFF_ET = 8448;
constexpr int OFF_PL = 16896;
// byte offsets for f32 scalar regions:
constexpr int OFF_SUMI = 50688;   // f32[32][4]
constexpr int OFF_SUMT = 51200;   // f32[32][4]
constexpr int OFF_ATT  = 51712;   // f32[32][4][2]
constexpr int OFF_SELB = 52736;   // f32[32]
constexpr int OFF_SELI = 52864;
constexpr int OFF_SELT = 52992;
constexpr int SMEM_BYTES = 53120; // 53.1KB -> 3 blocks/CU (159360 <= 163840)

// ============================ setup kernel ============================
// blocks: [0,512) WieT | [512,1024) WteT | [1024,1280) WvT | [1280,1792) WipT
// [1792,2304) WtpT | [2304,2816) Wc1T | [2816,2896) Wc2T | [2896,3408) WofT
// [3408] wkeff+sbias | [3409,3411) biasof
__global__ void aecf_setup(const float* __restrict__ W_ie, const float* __restrict__ W_te,
                           const float* __restrict__ fq,   const float* __restrict__ Wq,
                           const float* __restrict__ bq,   const float* __restrict__ Wk,
                           const float* __restrict__ bk,   const float* __restrict__ Wv,
                           const float* __restrict__ Wo,   const float* __restrict__ bo,
                           const float* __restrict__ W_ip, const float* __restrict__ W_tp,
                           const float* __restrict__ W_fp, const float* __restrict__ b_fp,
                           const float* __restrict__ Wc1,  const float* __restrict__ Wc2)
{
    __shared__ float qv[256];
    int b = blockIdx.x, t = threadIdx.x;

    if (b < 512) { int e = b*256+t; int k=e>>8, n=e&255; g_WieT[n*512+k] = (_Float16)W_ie[e]; return; }
    b -= 512;
    if (b < 512) { int e = b*256+t; int k=e>>8, n=e&255; g_WteT[n*512+k] = (_Float16)W_te[e]; return; }
    b -= 512;
    if (b < 256) { int e = b*256+t; int k=e>>8, n=e&255; g_WvT[n*256+k] = (_Float16)Wv[e]; return; }
    b -= 256;
    if (b < 512) { int e = b*256+t; int k=e>>9, n=e&511; g_WipT[n*256+k] = (_Float16)W_ip[e]; return; }
    b -= 512;
    if (b < 512) { int e = b*256+t; int k=e>>9, n=e&511; g_WtpT[n*256+k] = (_Float16)W_tp[e]; return; }
    b -= 512;
    if (b < 512) { int e = b*256+t; int k=e>>8, n=e&255; g_Wc1T[n*512+k] = (_Float16)Wc1[e]; return; }
    b -= 512;
    if (b < 80)  { int e = b*256+t; int k=e/80, n=e%80;  g_Wc2T[n*256+k] = (_Float16)Wc2[e]; return; }
    b -= 80;
    if (b < 512) {               // WofT row n = b : (Wo @ W_fp)^T
        int n = b, c = t;
        float s = 0.f;
        for (int m = 0; m < 256; m++) s += Wo[c*256+m] * W_fp[m*512+n];
        g_WofT[n*256+c] = (_Float16)s;
        return;
    }
    b -= 512;
    if (b == 0) {                // q = fq@Wq+bq ; wk_eff ; sbias
        float a = bq[t];
        for (int i = 0; i < 256; i++) a += fq[i] * Wq[i*256+t];
        qv[t] = a;
        __syncthreads();
        for (int h = 0; h < 4; h++) {
            float s = 0.f;
            for (int d = 0; d < 64; d++) s += Wk[t*256 + h*64+d] * qv[h*64+d];
            g_wkeff[h*256 + t] = s * 0.125f;           // [h][c] layout for vector loads
        }
        if (t < 4) {
            float s = 0.f;
            for (int d = 0; d < 64; d++) s += bk[t*64+d] * qv[t*64+d];
            g_sbias[t] = s * 0.125f;
        }
        return;
    }
    b -= 1;
    {                            // biasof = bo@W_fp + b_fp
        int n = b*256 + t;
        float s = b_fp[n];
        for (int m = 0; m < 256; m++) s += bo[m] * W_fp[m*512+n];
        g_biasof[n] = s;
    }
}

// ============================ main fused kernel ============================
__global__ __launch_bounds__(256, 3)
void aecf_main(const float* __restrict__ img, const float* __restrict__ txt,
               const float* __restrict__ b_ie, const float* __restrict__ b_te,
               const float* __restrict__ bv,   const float* __restrict__ b_ip,
               const float* __restrict__ b_tp, const float* __restrict__ bc1,
               const float* __restrict__ bc2,  float* __restrict__ out)
{
    extern __shared__ char smem[];
    _Float16* encI  = (_Float16*)smem + OFF_EI;   // [32][264]
    _Float16* encT  = (_Float16*)smem + OFF_ET;   // [32][264]
    _Float16* pool  = (_Float16*)smem + OFF_PL;   // [32][264], later h1
    _Float16* fused = (_Float16*)smem;            // [32][520] overlays encI+encT
    _Float16* h1    = pool;
    float* sumI = (float*)(smem + OFF_SUMI);
    float* sumT = (float*)(smem + OFF_SUMT);
    float* attn = (float*)(smem + OFF_ATT);
    float* selb = (float*)(smem + OFF_SELB);
    float* seli = (float*)(smem + OFF_SELI);
    float* selt = (float*)(smem + OFF_SELT);

    const int tid  = threadIdx.x;
    const int w    = tid >> 6;      // wave 0..3
    const int lane = tid & 63;
    const int l16  = lane & 15;
    const int q4   = lane >> 4;
    const int base = blockIdx.x * MROWS;

    // ---------------- stage 1: encoders (A direct from global + cvt) ----------------
    auto encode = [&](const float* __restrict__ src, const _Float16* __restrict__ WT,
                      const float* __restrict__ bias, _Float16* dstE, float* sumLds) {
        floatx4 acc[2][4];
        #pragma unroll
        for (int rt = 0; rt < 2; rt++)
            #pragma unroll
            for (int ct = 0; ct < 4; ct++) acc[rt][ct] = (floatx4){0.f,0.f,0.f,0.f};
        float sab[2] = {0.f, 0.f};

        for (int ks = 0; ks < 16; ks++) {
            const int k0 = ks*32 + q4*8;
            half8 afr[2];
            #pragma unroll
            for (int rt = 0; rt < 2; rt++) {
                const float* p = src + (size_t)(base + rt*16 + l16)*ID + k0;
                floatx4 x0 = *(const floatx4*)p;
                floatx4 x1 = *(const floatx4*)(p+4);
                half8 a;
                a[0]=(_Float16)x0[0]; a[1]=(_Float16)x0[1]; a[2]=(_Float16)x0[2]; a[3]=(_Float16)x0[3];
                a[4]=(_Float16)x1[0]; a[5]=(_Float16)x1[1]; a[6]=(_Float16)x1[2]; a[7]=(_Float16)x1[3];
                afr[rt] = a;
                if (w == 0)   // presence detection: wave0 accumulates |x| partials
                    sab[rt] += fabsf(x0[0])+fabsf(x0[1])+fabsf(x0[2])+fabsf(x0[3])
                             + fabsf(x1[0])+fabsf(x1[1])+fabsf(x1[2])+fabsf(x1[3]);
            }
            #pragma unroll
            for (int ct = 0; ct < 4; ct++) {
                const int ng = w*64 + ct*16 + l16;
                half8 bfr = *(const half8*)(WT + (size_t)ng*512 + k0);
                #pragma unroll
                for (int rt = 0; rt < 2; rt++) acc[rt][ct] = MFMA16(afr[rt], bfr, acc[rt][ct]);
            }
        }
        #pragma unroll
        for (int ct = 0; ct < 4; ct++) {
            const int colg = w*64 + ct*16 + l16;
            const float bb = bias[colg];
            #pragma unroll
            for (int rt = 0; rt < 2; rt++)
                #pragma unroll
                for (int r = 0; r < 4; r++) {
                    float v = acc[rt][ct][r] + bb;
                    v = v > 0.f ? v : 0.f;                     // relu
                    dstE[(rt*16 + q4*4 + r)*264 + colg] = (_Float16)v;
                }
        }
        if (w == 0) {
            #pragma unroll
            for (int rt = 0; rt < 2; rt++) sumLds[(rt*16 + l16)*4 + q4] = sab[rt];
        }
    };
    encode(img, g_WieT, b_ie, encI, sumI);
    encode(txt, g_WteT, b_te, encT, sumT);
    __syncthreads();   // B1

    // ---------------- stage 2: flags + scores + softmax (vectorized) ----------------
    if (tid < 128) {
        const int row = tid >> 2, h = tid & 3;
        float sI = sumI[row*4]+sumI[row*4+1]+sumI[row*4+2]+sumI[row*4+3];
        float sT = sumT[row*4]+sumT[row*4+1]+sumT[row*4+2]+sumT[row*4+3];
        bool pi = sI > 0.f, pt = sT > 0.f;
        if (h == 0) {
            selb[row] = (pi && pt)  ? 1.f : 0.f;
            seli[row] = (pi && !pt) ? 1.f : 0.f;
            selt[row] = (!pi && pt) ? 1.f : 0.f;
        }
        float s0 = g_sbias[h], s1 = s0;
        const _Float16* rI = encI + row*264;
        const _Float16* rT = encT + row*264;
        const float* wkh = g_wkeff + h*256;
        for (int c8 = 0; c8 < 256; c8 += 8) {
            half8 eI = *(const half8*)(rI + c8);
            half8 eT = *(const half8*)(rT + c8);
            floatx4 wa = *(const floatx4*)(wkh + c8);
            floatx4 wb = *(const floatx4*)(wkh + c8 + 4);
            s0 += wa[0]*(float)eI[0] + wa[1]*(float)eI[1] + wa[2]*(float)eI[2] + wa[3]*(float)eI[3]
                + wb[0]*(float)eI[4] + wb[1]*(float)eI[5] + wb[2]*(float)eI[6] + wb[3]*(float)eI[7];
            s1 += wa[0]*(float)eT[0] + wa[1]*(float)eT[1] + wa[2]*(float)eT[2] + wa[3]*(float)eT[3]
                + wb[0]*(float)eT[4] + wb[1]*(float)eT[5] + wb[2]*(float)eT[6] + wb[3]*(float)eT[7];
        }
        const float a0 = 1.f / (1.f + __expf(s1 - s0));
        attn[(row*4+h)*2]   = a0;
        attn[(row*4+h)*2+1] = 1.f - a0;
    }
    __syncthreads();   // B2

    // ---------------- stage 3: attention pooling FIRST (low reg pressure) ----------------
    {
        floatx4 poolacc[4][2];
        #pragma unroll
        for (int h = 0; h < 4; h++)
            #pragma unroll
            for (int rt = 0; rt < 2; rt++) poolacc[h][rt] = (floatx4){0.f,0.f,0.f,0.f};

        #pragma unroll
        for (int h = 0; h < 4; h++) {
            _Float16 a0l[2], a1l[2];
            #pragma unroll
            for (int rt = 0; rt < 2; rt++) {
                const int rr = rt*16 + l16;
                a0l[rt] = (_Float16)attn[(rr*4+h)*2];
                a1l[rt] = (_Float16)attn[(rr*4+h)*2+1];
            }
            const int ng = h*64 + w*16 + l16;
            for (int ks = 0; ks < 8; ks++) {
                const int k0 = ks*32 + q4*8;
                half8 bfr = *(const half8*)(g_WvT + (size_t)ng*256 + k0);
                #pragma unroll
                for (int rt = 0; rt < 2; rt++) {
                    half8 eI = *(const half8*)(encI + (rt*16+l16)*264 + k0);
                    half8 eT = *(const half8*)(encT + (rt*16+l16)*264 + k0);
                    half8 m  = eI * splat8(a0l[rt]) + eT * splat8(a1l[rt]);
                    poolacc[h][rt] = MFMA16(m, bfr, poolacc[h][rt]);
                }
            }
        }
        // write pool (own region; selb applied here so stage 4 needs no extra scale)
        #pragma unroll
        for (int h = 0; h < 4; h++) {
            const int colg = h*64 + w*16 + l16;
            const float bvv = bv[colg];
            #pragma unroll
            for (int rt = 0; rt < 2; rt++)
                #pragma unroll
                for (int r = 0; r < 4; r++) {
                    const int row = rt*16 + q4*4 + r;
                    pool[row*264 + colg] = (_Float16)((poolacc[h][rt][r] + bvv) * selb[row]);
                }
        }
    }
    __syncthreads();   // B3 (pool visible to all waves)

    // ---------------- stage 4: all three projections into one accumulator ----------------
    floatx4 pacc[2][8];
    #pragma unroll
    for (int rt = 0; rt < 2; rt++)
        #pragma unroll
        for (int ct = 0; ct < 8; ct++) pacc[rt][ct] = (floatx4){0.f,0.f,0.f,0.f};

    {   // img_out contribution: (seli * encI) @ W_ip
        _Float16 s[2];
        #pragma unroll
        for (int rt = 0; rt < 2; rt++) s[rt] = (_Float16)seli[rt*16 + l16];
        for (int ks = 0; ks < 8; ks++) {
            const int k0 = ks*32 + q4*8;
            half8 afr[2];
            #pragma unroll
            for (int rt = 0; rt < 2; rt++)
                afr[rt] = (*(const half8*)(encI + (rt*16+l16)*264 + k0)) * splat8(s[rt]);
            #pragma unroll
            for (int ct = 0; ct < 8; ct++) {
                const int ng = w*128 + ct*16 + l16;
                half8 bfr = *(const half8*)(g_WipT + (size_t)ng*256 + k0);
                #pragma unroll
                for (int rt = 0; rt < 2; rt++) pacc[rt][ct] = MFMA16(afr[rt], bfr, pacc[rt][ct]);
            }
        }
    }
    {   // txt_out contribution: (selt * encT) @ W_tp
        _Float16 s[2];
        #pragma unroll
        for (int rt = 0; rt < 2; rt++) s[rt] = (_Float16)selt[rt*16 + l16];
        for (int ks = 0; ks < 8; ks++) {
            const int k0 = ks*32 + q4*8;
            half8 afr[2];
            #pragma unroll
            for (int rt = 0; rt < 2; rt++)
                afr[rt] = (*(const half8*)(encT + (rt*16+l16)*264 + k0)) * splat8(s[rt]);
            #pragma unroll
            for (int ct = 0; ct < 8; ct++) {
                const int ng = w*128 + ct*16 + l16;
                half8 bfr = *(const half8*)(g_WtpT + (size_t)ng*256 + k0);
                #pragma unroll
                for (int rt = 0; rt < 2; rt++) pacc[rt][ct] = MFMA16(afr[rt], bfr, pacc[rt][ct]);
            }
        }
    }
    {   // fusion contribution: pool @ Wof (selb already folded into pool)
        for (int ks = 0; ks < 8; ks++) {
            const int k0 = ks*32 + q4*8;
            half8 afr[2];
            #pragma unroll
            for (int rt = 0; rt < 2; rt++)
                afr[rt] = *(const half8*)(pool + (rt*16+l16)*264 + k0);
            #pragma unroll
            for (int ct = 0; ct < 8; ct++) {
                const int ng = w*128 + ct*16 + l16;
                half8 bfr = *(const half8*)(g_WofT + (size_t)ng*256 + k0);
                #pragma unroll
                for (int rt = 0; rt < 2; rt++) pacc[rt][ct] = MFMA16(afr[rt], bfr, pacc[rt][ct]);
            }
        }
    }
    __syncthreads();   // B4 (all reads of encI/encT/pool done; fused overlays encI+encT)

    // fused = pacc + branch bias -> fp16 LDS
    {
        float sB[8], sI2[8], sT2[8];
        #pragma unroll
        for (int rt = 0; rt < 2; rt++)
            #pragma unroll
            for (int r = 0; r < 4; r++) {
                const int row = rt*16 + q4*4 + r;
                sB[rt*4+r] = selb[row]; sI2[rt*4+r] = seli[row]; sT2[rt*4+r] = selt[row];
            }
        #pragma unroll
        for (int ct = 0; ct < 8; ct++) {
            const int colg = w*128 + ct*16 + l16;
            const float bof = g_biasof[colg], bip = b_ip[colg], btp = b_tp[colg];
            #pragma unroll
            for (int rt = 0; rt < 2; rt++)
                #pragma unroll
                for (int r = 0; r < 4; r++) {
                    const int row = rt*16 + q4*4 + r;
                    const float f = pacc[rt][ct][r] + sB[rt*4+r]*bof + sI2[rt*4+r]*bip + sT2[rt*4+r]*btp;
                    fused[row*520 + colg] = (_Float16)f;
                }
        }
    }
    __syncthreads();   // B5

    // ---------------- stage 5: classifier layer 1 ----------------
    {
        floatx4 cacc[2][4];
        #pragma unroll
        for (int rt = 0; rt < 2; rt++)
            #pragma unroll
            for (int ct = 0; ct < 4; ct++) cacc[rt][ct] = (floatx4){0.f,0.f,0.f,0.f};
        for (int ks = 0; ks < 16; ks++) {
            const int k0 = ks*32 + q4*8;
            half8 afr[2];
            #pragma unroll
            for (int rt = 0; rt < 2; rt++)
                afr[rt] = *(const half8*)(fused + (rt*16+l16)*520 + k0);
            #pragma unroll
            for (int ct = 0; ct < 4; ct++) {
                const int ng = w*64 + ct*16 + l16;
                half8 bfr = *(const half8*)(g_Wc1T + (size_t)ng*512 + k0);
                #pragma unroll
                for (int rt = 0; rt < 2; rt++) cacc[rt][ct] = MFMA16(afr[rt], bfr, cacc[rt][ct]);
            }
        }
        __syncthreads();   // B6a: fused reads done; h1 overlays pool (separate region, but
                           // keep barrier before h1 writes are consumed below anyway)
        #pragma unroll
        for (int ct = 0; ct < 4; ct++) {
            const int colg = w*64 + ct*16 + l16;
            const float b1 = bc1[colg];
            #pragma unroll
            for (int rt = 0; rt < 2; rt++)
                #pragma unroll
                for (int r = 0; r < 4; r++) {
                    float v = cacc[rt][ct][r] + b1;
                    v = v > 0.f ? v : 0.f;                         // relu
                    h1[(rt*16 + q4*4 + r)*264 + colg] = (_Float16)v;
                }
        }
    }
    __syncthreads();   // B6

    // ---------------- stage 6: classifier layer 2 + store ----------------
    for (int p = w; p < 10; p += 4) {          // 10 (rt,ct) tile pairs over [32][80]
        const int rt = p / 5, ct = p % 5;
        const int ng = ct*16 + l16;
        floatx4 a2 = (floatx4){0.f,0.f,0.f,0.f};
        for (int ks = 0; ks < 8; ks++) {
            const int k0 = ks*32 + q4*8;
            half8 afr = *(const half8*)(h1 + (rt*16+l16)*264 + k0);
            half8 bfr = *(const half8*)(g_Wc2T + (size_t)ng*256 + k0);
            a2 = MFMA16(afr, bfr, a2);
        }
        const float b2 = bc2[ng];
        #pragma unroll
        for (int r = 0; r < 4; r++) {
            const int rowg = base + rt*16 + q4*4 + r;
            out[(size_t)rowg*NC + ng] = a2[r] + b2;
        }
    }
}

// ============================ launch ============================
extern "C" void kernel_launch(void* const* d_in, const int* in_sizes, int n_in,
                              void* d_out, int out_size, void* d_ws, size_t ws_size,
                              hipStream_t stream)
{
    const float* img  = (const float*)d_in[0];
    const float* txt  = (const float*)d_in[1];
    const float* W_ie = (const float*)d_in[2];
    const float* b_ie = (const float*)d_in[3];
    const float* W_te = (const float*)d_in[4];
    const float* b_te = (const float*)d_in[5];
    const float* fq   = (const float*)d_in[6];
    const float* Wq   = (const float*)d_in[7];
    const float* bq   = (const float*)d_in[8];
    const float* Wk   = (const float*)d_in[9];
    const float* bk   = (const float*)d_in[10];
    const float* Wv   = (const float*)d_in[11];
    const float* bv   = (const float*)d_in[12];
    const float* Wo   = (const float*)d_in[13];
    const float* bo   = (const float*)d_in[14];
    const float* W_ip = (const float*)d_in[15];
    const float* b_ip = (const float*)d_in[16];
    const float* W_tp = (const float*)d_in[17];
    const float* b_tp = (const float*)d_in[18];
    const float* W_fp = (const float*)d_in[19];
    const float* b_fp = (const float*)d_in[20];
    const float* Wc1  = (const float*)d_in[21];
    const float* bc1  = (const float*)d_in[22];
    const float* Wc2  = (const float*)d_in[23];
    const float* bc2  = (const float*)d_in[24];
    float* out = (float*)d_out;

    hipFuncSetAttribute((const void*)aecf_main,
                        hipFuncAttributeMaxDynamicSharedMemorySize, SMEM_BYTES);

    aecf_setup<<<3411, 256, 0, stream>>>(W_ie, W_te, fq, Wq, bq, Wk, bk, Wv,
                                         Wo, bo, W_ip, W_tp, W_fp, b_fp, Wc1, Wc2);
    aecf_main<<<NBLK, 256, SMEM_BYTES, stream>>>(img, txt, b_ie, b_te, bv,
                                                 b_ip, b_tp, bc1, bc2, out);
}